// Round 1
// baseline (248.699 us; speedup 1.0000x reference)
//
#include <hip/hip_runtime.h>

typedef short short8 __attribute__((ext_vector_type(8)));
typedef float f32x4 __attribute__((ext_vector_type(4)));
typedef unsigned short u16;

#define MFMA16(a, b, c) __builtin_amdgcn_mfma_f32_16x16x32_bf16(a, b, c, 0, 0, 0)
#define GLD_LDS(g, l)                                                          \
  __builtin_amdgcn_global_load_lds(                                            \
      (__attribute__((address_space(1))) void*)(void*)(g),                     \
      (__attribute__((address_space(3))) void*)(l), 16, 0, 0)

__device__ __forceinline__ u16 f2bf(float f) {
  union { float f; unsigned u; } x; x.f = f;
  unsigned r = x.u + 0x7fffu + ((x.u >> 16) & 1u);
  return (u16)(r >> 16);
}

__device__ __forceinline__ short8 pack8(float4 a, float4 b) {
  short8 r;
  r[0] = (short)f2bf(a.x); r[1] = (short)f2bf(a.y);
  r[2] = (short)f2bf(a.z); r[3] = (short)f2bf(a.w);
  r[4] = (short)f2bf(b.x); r[5] = (short)f2bf(b.y);
  r[6] = (short)f2bf(b.z); r[7] = (short)f2bf(b.w);
  return r;
}

// ---------------- kernel 0: WoT[n][k] = bf16(Wo[k][n]) ----------------
__global__ __launch_bounds__(256) void prep_wo(const float* __restrict__ Wo,
                                               u16* __restrict__ WoT) {
  __shared__ __align__(16) float tile[64][68];
  const int t = threadIdx.x;
  const int tr = blockIdx.x & 15, tc = blockIdx.x >> 4; // k-tile, n-tile
  const int r = t >> 2, c4 = (t & 3) * 16;
  const float* src = Wo + (tr * 64 + r) * 1024 + tc * 64 + c4;
  float4 a0 = ((const float4*)src)[0];
  float4 a1 = ((const float4*)src)[1];
  float4 a2 = ((const float4*)src)[2];
  float4 a3 = ((const float4*)src)[3];
  *(float4*)&tile[r][c4 + 0]  = a0;
  *(float4*)&tile[r][c4 + 4]  = a1;
  *(float4*)&tile[r][c4 + 8]  = a2;
  *(float4*)&tile[r][c4 + 12] = a3;
  __syncthreads();
  short8 o0, o1;
#pragma unroll
  for (int j = 0; j < 8; ++j) o0[j] = (short)f2bf(tile[c4 + j][r]);
#pragma unroll
  for (int j = 0; j < 8; ++j) o1[j] = (short)f2bf(tile[c4 + 8 + j][r]);
  u16* dst = WoT + (size_t)(tc * 64 + r) * 1024 + tr * 64 + c4;
  *(short8*)(void*)dst = o0;
  *(short8*)(void*)(dst + 8) = o1;
}

// ---------------- kernel 1: projections + head-softmax + PV + scramble ----
// 1 wave handles 8 consecutive positions (n,l). Writes attention (fp32) and
// out2 (bf16, already in the transpose(0,2,1,3).reshape layout).
__global__ __launch_bounds__(256, 2) void attn_kernel(
    const float* __restrict__ values, const float* __restrict__ keys,
    const float* __restrict__ query, const int* __restrict__ mask,
    const float* __restrict__ Wv, const float* __restrict__ Wk,
    const float* __restrict__ Wq, float* __restrict__ attn,
    u16* __restrict__ out2) {
  __shared__ __align__(16) u16 q_lds[4][16][72];   // [wave][h][d] pad->2-way
  __shared__ __align__(16) u16 k_lds[4][16][72];
  __shared__ __align__(16) u16 p_lds[4][16][24];   // [wave][h][g]
  __shared__ __align__(16) u16 vT_lds[4][64][24];  // [wave][d][g]

  const int tid = threadIdx.x;
  const int w = tid >> 6, lane = tid & 63;
  const int g16 = lane & 15;  // col-of-frag / A-row
  const int q4 = lane >> 4;   // k-chunk selector
  const int kbase = q4 * 8;   // A/B frag k offset
  const int mrow = q4 * 4;    // D-frag row base

  // Weight B-fragments, resident in registers for the whole kernel.
  short8 wqf[2][4], wkf[2][4], wvf[2][4];
#pragma unroll
  for (int kb = 0; kb < 2; ++kb)
#pragma unroll
    for (int nc = 0; nc < 4; ++nc) {
#pragma unroll
      for (int j = 0; j < 8; ++j) {
        const int kk = (kb * 32 + kbase + j) * 64 + nc * 16 + g16;
        wqf[kb][nc][j] = (short)f2bf(Wq[kk]);
        wkf[kb][nc][j] = (short)f2bf(Wk[kk]);
        wvf[kb][nc][j] = (short)f2bf(Wv[kk]);
      }
    }

  bool mz[4];
#pragma unroll
  for (int r = 0; r < 4; ++r) mz[r] = (mask[(mrow + r) * 16 + g16] == 0);

  const f32x4 zero = {0.f, 0.f, 0.f, 0.f};
  const int gw = blockIdx.x * 4 + w;

  for (int i = 0; i < 8; ++i) {
    const int p = gw * 8 + i;
    const int nn = p >> 12, l = p & 4095;
    const int xbase = (nn * 4096 + l) * 1024;

    // load x rows (head = g16), convert to A-fragments
    short8 aq[2], ak[2], av[2];
#pragma unroll
    for (int kb = 0; kb < 2; ++kb) {
      const int off = xbase + g16 * 64 + kb * 32 + kbase;
      float4 u0 = *(const float4*)(query + off);
      float4 u1 = *(const float4*)(query + off + 4);
      float4 k0 = *(const float4*)(keys + off);
      float4 k1 = *(const float4*)(keys + off + 4);
      float4 v0 = *(const float4*)(values + off);
      float4 v1 = *(const float4*)(values + off + 4);
      aq[kb] = pack8(u0, u1);
      ak[kb] = pack8(k0, k1);
      av[kb] = pack8(v0, v1);
    }

    // projections: D[h][dout] per 16-col tile
    f32x4 accq[4], acck[4], accv[4];
#pragma unroll
    for (int nc = 0; nc < 4; ++nc) {
      accq[nc] = zero; acck[nc] = zero; accv[nc] = zero;
#pragma unroll
      for (int kb = 0; kb < 2; ++kb) {
        accq[nc] = MFMA16(aq[kb], wqf[kb][nc], accq[nc]);
        acck[nc] = MFMA16(ak[kb], wkf[kb][nc], acck[nc]);
        accv[nc] = MFMA16(av[kb], wvf[kb][nc], accv[nc]);
      }
    }
#pragma unroll
    for (int nc = 0; nc < 4; ++nc)
#pragma unroll
      for (int r = 0; r < 4; ++r) {
        q_lds[w][mrow + r][nc * 16 + g16] = f2bf(accq[nc][r]);
        k_lds[w][mrow + r][nc * 16 + g16] = f2bf(acck[nc][r]);
        vT_lds[w][nc * 16 + g16][mrow + r] = f2bf(accv[nc][r]);
      }
    __builtin_amdgcn_sched_barrier(0);

    // energy = q @ k^T  (A row = h = g16, B col = g = g16)
    short8 ea0 = *(const short8*)&q_lds[w][g16][kbase];
    short8 ea1 = *(const short8*)&q_lds[w][g16][32 + kbase];
    short8 eb0 = *(const short8*)&k_lds[w][g16][kbase];
    short8 eb1 = *(const short8*)&k_lds[w][g16][32 + kbase];
    f32x4 acce = zero;
    acce = MFMA16(ea0, eb0, acce);
    acce = MFMA16(ea1, eb1, acce);

    // masked softmax across g (16 lanes), rows h = mrow+r
    float av4[4];
#pragma unroll
    for (int r = 0; r < 4; ++r) {
      float val = mz[r] ? -3.125e18f : acce[r] * 0.03125f;
      float mx = val;
      mx = fmaxf(mx, __shfl_xor(mx, 1, 16));
      mx = fmaxf(mx, __shfl_xor(mx, 2, 16));
      mx = fmaxf(mx, __shfl_xor(mx, 4, 16));
      mx = fmaxf(mx, __shfl_xor(mx, 8, 16));
      float pe = __expf(val - mx);
      float s = pe;
      s += __shfl_xor(s, 1, 16);
      s += __shfl_xor(s, 2, 16);
      s += __shfl_xor(s, 4, 16);
      s += __shfl_xor(s, 8, 16);
      av4[r] = pe / s;
    }
    float* ap = attn + (size_t)(nn * 4096 + l) * 256 + mrow * 16 + g16;
#pragma unroll
    for (int r = 0; r < 4; ++r) {
      ap[r * 16] = av4[r];
      p_lds[w][mrow + r][g16] = f2bf(av4[r]);
    }
    __builtin_amdgcn_sched_barrier(0);

    // o = P @ v : A = P (K=16 padded to 32 with zero frags), B = v[g][d]
    short8 pa;
    if (lane < 32) {
      pa = *(const short8*)&p_lds[w][g16][kbase];
    } else {
      short8 z = {0, 0, 0, 0, 0, 0, 0, 0};
      pa = z;
    }
    const int gsel = (lane < 32) ? kbase : 0;  // clamp: avoid NaN*0 from junk
#pragma unroll
    for (int nc = 0; nc < 4; ++nc) {
      short8 vb = *(const short8*)&vT_lds[w][nc * 16 + g16][gsel];
      f32x4 acco = MFMA16(pa, vb, zero);
#pragma unroll
      for (int r = 0; r < 4; ++r) {
        const int h = mrow + r, d = nc * 16 + g16;
        const int idx =
            (nn * 4096 + h * 256 + (l >> 4)) * 1024 + (l & 15) * 64 + d;
        out2[idx] = f2bf(acco[r]);
      }
    }
    __builtin_amdgcn_sched_barrier(0);
  }
}

// ---------------- kernel 2: out = out2(bf16) @ Wo + bo (m97 structure) ----
__global__ __launch_bounds__(256, 2) void gemm_kernel(
    const u16* __restrict__ A, const u16* __restrict__ BT,
    const float* __restrict__ bo, float* __restrict__ C) {
  __shared__ __align__(16) u16 As[128 * 32];
  __shared__ __align__(16) u16 Bs[128 * 32];
  const int t = threadIdx.x, lane = t & 63;
  const int g16 = lane & 15, q4 = lane >> 4;
  const int w = t >> 6, wm = w >> 1, wn = w & 1;
  const int bm = blockIdx.x & 255, bn = blockIdx.x >> 8;

  f32x4 acc[4][4];
  const f32x4 zero = {0.f, 0.f, 0.f, 0.f};
#pragma unroll
  for (int mt = 0; mt < 4; ++mt)
#pragma unroll
    for (int nt = 0; nt < 4; ++nt) acc[mt][nt] = zero;

  const int am = t >> 2, ak = (t & 3) * 8;
  const u16* ga = A + (size_t)(bm * 128 + am) * 1024 + ak;
  const u16* gb = BT + (size_t)(bn * 128 + am) * 1024 + ak;
  u16* lA = &As[t * 8];
  u16* lB = &Bs[t * 8];

  for (int kt = 0; kt < 32; ++kt) {
    __syncthreads();  // previous tile's reads complete
    const int ko = kt * 32;
    GLD_LDS(ga + ko, lA);
    GLD_LDS(ga + 64 * 1024 + ko, lA + 2048);
    GLD_LDS(gb + ko, lB);
    GLD_LDS(gb + 64 * 1024 + ko, lB + 2048);
    __syncthreads();  // barrier drains vmcnt: staging visible

    short8 af[4], bf[4];
#pragma unroll
    for (int mt = 0; mt < 4; ++mt)
      af[mt] = *(const short8*)&As[(wm * 64 + mt * 16 + g16) * 32 + q4 * 8];
#pragma unroll
    for (int nt = 0; nt < 4; ++nt)
      bf[nt] = *(const short8*)&Bs[(wn * 64 + nt * 16 + g16) * 32 + q4 * 8];
#pragma unroll
    for (int mt = 0; mt < 4; ++mt)
#pragma unroll
      for (int nt = 0; nt < 4; ++nt)
        acc[mt][nt] = MFMA16(af[mt], bf[nt], acc[mt][nt]);
  }

#pragma unroll
  for (int nt = 0; nt < 4; ++nt) {
    const int col = bn * 128 + wn * 64 + nt * 16 + g16;
    const float bias = bo[col];
#pragma unroll
    for (int mt = 0; mt < 4; ++mt) {
#pragma unroll
      for (int r = 0; r < 4; ++r) {
        const int row = bm * 128 + wm * 64 + mt * 16 + q4 * 4 + r;
        C[(size_t)row * 1024 + col] = acc[mt][nt][r] + bias;
      }
    }
  }
}

extern "C" void kernel_launch(void* const* d_in, const int* in_sizes, int n_in,
                              void* d_out, int out_size, void* d_ws,
                              size_t ws_size, hipStream_t stream) {
  const float* values = (const float*)d_in[0];
  const float* keys   = (const float*)d_in[1];
  const float* query  = (const float*)d_in[2];
  const int*   mask   = (const int*)d_in[3];
  const float* Wv = (const float*)d_in[4];
  const float* Wk = (const float*)d_in[5];
  const float* Wq = (const float*)d_in[6];
  const float* Wo = (const float*)d_in[7];
  const float* bo = (const float*)d_in[8];

  float* out  = (float*)d_out;        // 8*4096*1024 = 33554432 fp32
  float* attn = out + 33554432;       // 8*4096*16*16 = 8388608 fp32

  u16* out2 = (u16*)d_ws;             // 32768 x 1024 bf16 (64 MiB)
  u16* WoT  = out2 + 33554432;        // 1024 x 1024 bf16 (2 MiB)

  prep_wo<<<256, 256, 0, stream>>>(Wo, WoT);
  attn_kernel<<<1024, 256, 0, stream>>>(values, keys, query, mask, Wv, Wk, Wq,
                                        attn, out2);
  gemm_kernel<<<2048, 256, 0, stream>>>(out2, WoT, bo, out);
}